// Round 2
// baseline (39.694 us; speedup 1.0000x reference)
//
#include <hip/hip_runtime.h>
#include <hip/hip_bf16.h>

// SiameseConv: out[b,y,x,o] = sum_{i,j,c} det[b,y+i,x+j,c] * tmpl[b,i,j,c,o]
// det: [64,20,20,256] f32, tmpl: [64,4,4,256*20] f32 (last dim = [c][o]),
// out: [64,17,17,20] f32.
//
// Strategy: per-example GEMM C[289x20] = A[289x4096] x B[4096x20], K=(ij,c).
// K-split by channel chunks of 32 -> grid = 64 b x 8 chunks = 512 blocks,
// zero redundant global traffic (each block reads disjoint input slices).
// Stage bf16 slices in LDS (swizzled), 16x16x32 bf16 MFMA, atomicAdd partials.
// R1: replaced hipMemsetAsync (rocclr fillBuffer = 40us, the whole measured
// time) with a custom grid-strided float4 zero kernel (~2us).

typedef __bf16 bf16x8 __attribute__((ext_vector_type(8)));
typedef float f32x4 __attribute__((ext_vector_type(4)));

#define NB 64
#define C_TOT 256
#define CQ 32            // channels per block
#define NQ 8             // c-chunks (256/32)
#define NPOS 400         // 20*20 detection positions
#define NP 289           // 17*17 output positions
#define NO 20            // outputs per position
#define DET_LDS_BYTES (NPOS * CQ * 2)      // 25600: [400 pos][32 c] bf16
#define TMP_LDS_BYTES (16 * 32 * CQ * 2)   // 32768: [16 ij][32 o][32 c] bf16

__device__ __forceinline__ unsigned short f2bf(float f) {
  // round-to-nearest-even f32 -> bf16
  unsigned u = __builtin_bit_cast(unsigned, f);
  u += 0x7fffu + ((u >> 16) & 1u);
  return (unsigned short)(u >> 16);
}

__global__ __launch_bounds__(256)
void zero_out_kernel(float4* __restrict__ out, int n4) {
  int i = blockIdx.x * 256 + threadIdx.x;
  if (i < n4) out[i] = make_float4(0.f, 0.f, 0.f, 0.f);
}

__global__ __launch_bounds__(512, 4)
void siamese_kernel(const float* __restrict__ det,
                    const float* __restrict__ tmp,
                    float* __restrict__ out) {
  __shared__ alignas(16) char lds[DET_LDS_BYTES + TMP_LDS_BYTES];
  char* detB = lds;
  char* tmpB = lds + DET_LDS_BYTES;

  const int tid = threadIdx.x;
  const int b   = blockIdx.x >> 3;   // / NQ
  const int q   = blockIdx.x & 7;    // % NQ
  const int c0  = q * CQ;

  // ---- stage detection slice [400][32] bf16, granule-swizzled ----
  // rows are 64 B; swizzle 16B granule index g -> g ^ ((pos>>1)&3) so that
  // stride-64B reads across consecutive pos land on distinct bank quads.
  {
    const float* __restrict__ dsrc = det + (size_t)b * (NPOS * C_TOT);
    for (int it = tid; it < NPOS * CQ / 4; it += 512) {   // 3200 float4
      int pos = it >> 3;          // 8 float4 per pos
      int cg  = it & 7;
      const float4 v = *(const float4*)(dsrc + pos * C_TOT + c0 + cg * 4);
      unsigned long long pk =
          (unsigned long long)f2bf(v.x) |
          ((unsigned long long)f2bf(v.y) << 16) |
          ((unsigned long long)f2bf(v.z) << 32) |
          ((unsigned long long)f2bf(v.w) << 48);
      int byte = pos * 64 + (((cg >> 1) ^ ((pos >> 1) & 3)) << 4) + (cg & 1) * 8;
      *(unsigned long long*)(detB + byte) = pk;
    }
  }

  // ---- zero template pad rows (o in [20,32)) -> N-tile 1 cols read zeros ----
  {
    for (int z = tid; z < 16 * 12 * 4; z += 512) {   // 768 x 16B
      int rr = z >> 2;
      int ij = rr / 12;
      int o  = 20 + (rr % 12);
      int byte = (ij * 32 + o) * 64 + (z & 3) * 16;
      *(uint4*)(tmpB + byte) = make_uint4(0u, 0u, 0u, 0u);
    }
  }

  // ---- stage template slice transposed to [ij][o][c_local] bf16, swizzled ----
  // global layout is [ij][c][o] (o fastest); thread grabs 8 consecutive c at
  // fixed (ij,o) via 8 stride-80B loads (region is compact -> cache-friendly),
  // writes one 16B granule.
  {
    const float* __restrict__ tsrc = tmp + (size_t)b * (16 * C_TOT * NO);
    for (int it = tid; it < 16 * NO * (CQ / 8); it += 512) {   // 1280
      int ij = it / 80;
      int r  = it % 80;
      int o  = r >> 2;
      int cg = r & 3;            // which octet of c
      const float* src = tsrc + ij * (C_TOT * NO) + (c0 + cg * 8) * NO + o;
      unsigned short s[8];
      #pragma unroll
      for (int e = 0; e < 8; ++e) s[e] = f2bf(src[e * NO]);
      uint4 w;
      w.x = (unsigned)s[0] | ((unsigned)s[1] << 16);
      w.y = (unsigned)s[2] | ((unsigned)s[3] << 16);
      w.z = (unsigned)s[4] | ((unsigned)s[5] << 16);
      w.w = (unsigned)s[6] | ((unsigned)s[7] << 16);
      int row  = ij * 32 + o;
      int byte = row * 64 + (((cg ^ ((o >> 1) & 3)) << 4));
      *(uint4*)(tmpB + byte) = w;
    }
  }

  __syncthreads();

  // ---- compute: 19 M-tiles x 2 N-tiles over 8 waves, 16 K-steps of 32 ----
  const int w    = tid >> 6;
  const int lane = tid & 63;
  const int lo   = lane & 15;
  const int hi   = lane >> 4;
  const int nm   = (w < 3) ? 3 : 2;   // waves 0-2 own 3 M-tiles, rest own 2

  int posb[3];
  #pragma unroll
  for (int mi = 0; mi < 3; ++mi) {
    int m = w + mi * 8;                // M-tile index (w, w+8, w+16)
    int p = m * 16 + lo;               // A-row for this lane
    if (p > NP - 1) p = NP - 1;        // clamp pad rows (discarded at store)
    posb[mi] = (p / 17) * 20 + (p % 17);
  }

  f32x4 acc[3][2] = {};

  const int o0   = lo;                 // N-tile 0 col
  const int o1   = 16 + lo;            // N-tile 1 col (>=20 reads zeros)
  const int bad0 = (0 * 32 + o0) * 64 + ((hi ^ ((o0 >> 1) & 3)) << 4);
  const int bad1 = (0 * 32 + o1) * 64 + ((hi ^ ((o1 >> 1) & 3)) << 4);

  for (int ij = 0; ij < 16; ++ij) {
    const int i  = ij >> 2, j = ij & 3;
    const int sh = i * 20 + j;

    bf16x8 bf0 = *(const bf16x8*)(tmpB + bad0 + ij * (32 * 64));
    bf16x8 bf1 = *(const bf16x8*)(tmpB + bad1 + ij * (32 * 64));

    bf16x8 a[3];
    #pragma unroll
    for (int mi = 0; mi < 3; ++mi) {
      if (mi < nm) {
        int pos  = posb[mi] + sh;
        int byte = pos * 64 + ((hi ^ ((pos >> 1) & 3)) << 4);
        a[mi] = *(const bf16x8*)(detB + byte);
      }
    }
    #pragma unroll
    for (int mi = 0; mi < 3; ++mi) {
      if (mi < nm) {
        acc[mi][0] = __builtin_amdgcn_mfma_f32_16x16x32_bf16(a[mi], bf0, acc[mi][0], 0, 0, 0);
        acc[mi][1] = __builtin_amdgcn_mfma_f32_16x16x32_bf16(a[mi], bf1, acc[mi][1], 0, 0, 0);
      }
    }
  }

  // ---- accumulate partials to global (d_out pre-zeroed each launch) ----
  float* __restrict__ ob = out + (size_t)b * (NP * NO);
  #pragma unroll
  for (int mi = 0; mi < 3; ++mi) {
    if (mi < nm) {
      int m = w + mi * 8;
      #pragma unroll
      for (int n = 0; n < 2; ++n) {
        int o = n * 16 + lo;
        if (o < NO) {
          #pragma unroll
          for (int v = 0; v < 4; ++v) {
            int p = m * 16 + hi * 4 + v;   // C/D: row=(lane>>4)*4+reg, col=lane&15
            if (p < NP) atomicAdd(ob + p * NO + o, acc[mi][n][v]);
          }
        }
      }
    }
  }
}

extern "C" void kernel_launch(void* const* d_in, const int* in_sizes, int n_in,
                              void* d_out, int out_size, void* d_ws, size_t ws_size,
                              hipStream_t stream) {
  (void)in_sizes; (void)n_in; (void)d_ws; (void)ws_size;
  const float* det = (const float*)d_in[0];
  const float* tmp = (const float*)d_in[1];
  float* out = (float*)d_out;
  // zero output each launch with our own kernel (rocclr fillBuffer was 40us!)
  int n4 = out_size / 4;   // 369920 / 4 = 92480, exact
  zero_out_kernel<<<dim3((n4 + 255) / 256), dim3(256), 0, stream>>>((float4*)out, n4);
  siamese_kernel<<<dim3(NB * NQ), dim3(512), 0, stream>>>(det, tmp, out);
}

// Round 3
// 22.005 us; speedup vs baseline: 1.8039x; 1.8039x over previous
//
#include <hip/hip_runtime.h>
#include <hip/hip_bf16.h>

// SiameseConv: out[b,y,x,o] = sum_{i,j,c} det[b,y+i,x+j,c] * tmpl[b,i,j,c,o]
// det: [64,20,20,256] f32, tmpl: [64,4,4,256*20] f32 (last dim = [c][o]),
// out: [64,17,17,20] f32.
//
// Per-example GEMM C[289x20] = A[289x4096] x B[4096x20], K=(ij,c), K-split by
// channel chunk of 32 -> 512 blocks. Stage bf16 slices in LDS (swizzled),
// 16x16x32 bf16 MFMA.
// R2: epilogue was 2.96M cross-XCD device-scope fp32 atomicAdds (8-way
// same-address contention) == ~37us of the 39.7us total. Replaced with plain
// stores of per-block partial tiles to d_ws + a float4 tree-reduce kernel.

typedef __bf16 bf16x8 __attribute__((ext_vector_type(8)));
typedef float f32x4 __attribute__((ext_vector_type(4)));

#define NB 64
#define C_TOT 256
#define CQ 32            // channels per block
#define NQ 8             // c-chunks (256/32)
#define NPOS 400         // 20*20 detection positions
#define NP 289           // 17*17 output positions
#define NO 20            // outputs per position
#define PTILE (NP * NO)  // 5780 floats per partial tile
#define DET_LDS_BYTES (NPOS * CQ * 2)      // 25600: [400 pos][32 c] bf16
#define TMP_LDS_BYTES (16 * 32 * CQ * 2)   // 32768: [16 ij][32 o][32 c] bf16

__device__ __forceinline__ unsigned short f2bf(float f) {
  // round-to-nearest-even f32 -> bf16
  unsigned u = __builtin_bit_cast(unsigned, f);
  u += 0x7fffu + ((u >> 16) & 1u);
  return (unsigned short)(u >> 16);
}

// out[e] = sum_{q=0..7} ws[q*369920 + e], float4-vectorized.
__global__ __launch_bounds__(256)
void reduce_kernel(const float4* __restrict__ ws, float4* __restrict__ out, int n4) {
  int i = blockIdx.x * 256 + threadIdx.x;
  if (i >= n4) return;
  float4 s = ws[i];
  #pragma unroll
  for (int q = 1; q < NQ; ++q) {
    float4 v = ws[q * n4 + i];
    s.x += v.x; s.y += v.y; s.z += v.z; s.w += v.w;
  }
  out[i] = s;
}

__global__ __launch_bounds__(512, 4)
void siamese_kernel(const float* __restrict__ det,
                    const float* __restrict__ tmp,
                    float* __restrict__ ws) {
  __shared__ alignas(16) char lds[DET_LDS_BYTES + TMP_LDS_BYTES];
  char* detB = lds;
  char* tmpB = lds + DET_LDS_BYTES;

  const int tid = threadIdx.x;
  const int b   = blockIdx.x >> 3;   // / NQ
  const int q   = blockIdx.x & 7;    // % NQ
  const int c0  = q * CQ;

  // ---- stage detection slice [400][32] bf16, granule-swizzled ----
  {
    const float* __restrict__ dsrc = det + (size_t)b * (NPOS * C_TOT);
    for (int it = tid; it < NPOS * CQ / 4; it += 512) {   // 3200 float4
      int pos = it >> 3;          // 8 float4 per pos
      int cg  = it & 7;
      const float4 v = *(const float4*)(dsrc + pos * C_TOT + c0 + cg * 4);
      unsigned long long pk =
          (unsigned long long)f2bf(v.x) |
          ((unsigned long long)f2bf(v.y) << 16) |
          ((unsigned long long)f2bf(v.z) << 32) |
          ((unsigned long long)f2bf(v.w) << 48);
      int byte = pos * 64 + (((cg >> 1) ^ ((pos >> 1) & 3)) << 4) + (cg & 1) * 8;
      *(unsigned long long*)(detB + byte) = pk;
    }
  }

  // ---- zero template pad rows (o in [20,32)) ----
  {
    for (int z = tid; z < 16 * 12 * 4; z += 512) {   // 768 x 16B
      int rr = z >> 2;
      int ij = rr / 12;
      int o  = 20 + (rr % 12);
      int byte = (ij * 32 + o) * 64 + (z & 3) * 16;
      *(uint4*)(tmpB + byte) = make_uint4(0u, 0u, 0u, 0u);
    }
  }

  // ---- stage template slice transposed to [ij][o][c_local] bf16, swizzled ----
  {
    const float* __restrict__ tsrc = tmp + (size_t)b * (16 * C_TOT * NO);
    for (int it = tid; it < 16 * NO * (CQ / 8); it += 512) {   // 1280
      int ij = it / 80;
      int r  = it % 80;
      int o  = r >> 2;
      int cg = r & 3;            // which octet of c
      const float* src = tsrc + ij * (C_TOT * NO) + (c0 + cg * 8) * NO + o;
      unsigned short s[8];
      #pragma unroll
      for (int e = 0; e < 8; ++e) s[e] = f2bf(src[e * NO]);
      uint4 w;
      w.x = (unsigned)s[0] | ((unsigned)s[1] << 16);
      w.y = (unsigned)s[2] | ((unsigned)s[3] << 16);
      w.z = (unsigned)s[4] | ((unsigned)s[5] << 16);
      w.w = (unsigned)s[6] | ((unsigned)s[7] << 16);
      int row  = ij * 32 + o;
      int byte = row * 64 + (((cg ^ ((o >> 1) & 3)) << 4));
      *(uint4*)(tmpB + byte) = w;
    }
  }

  __syncthreads();

  // ---- compute: 19 M-tiles x 2 N-tiles over 8 waves, 16 K-steps of 32 ----
  const int w    = tid >> 6;
  const int lane = tid & 63;
  const int lo   = lane & 15;
  const int hi   = lane >> 4;
  const int nm   = (w < 3) ? 3 : 2;   // waves 0-2 own 3 M-tiles, rest own 2

  int posb[3];
  #pragma unroll
  for (int mi = 0; mi < 3; ++mi) {
    int m = w + mi * 8;                // M-tile index (w, w+8, w+16)
    int p = m * 16 + lo;               // A-row for this lane
    if (p > NP - 1) p = NP - 1;        // clamp pad rows (discarded at store)
    posb[mi] = (p / 17) * 20 + (p % 17);
  }

  f32x4 acc[3][2] = {};

  const int o0   = lo;                 // N-tile 0 col
  const int o1   = 16 + lo;            // N-tile 1 col (>=20 reads zeros)
  const int bad0 = (0 * 32 + o0) * 64 + ((hi ^ ((o0 >> 1) & 3)) << 4);
  const int bad1 = (0 * 32 + o1) * 64 + ((hi ^ ((o1 >> 1) & 3)) << 4);

  for (int ij = 0; ij < 16; ++ij) {
    const int i  = ij >> 2, j = ij & 3;
    const int sh = i * 20 + j;

    bf16x8 bf0 = *(const bf16x8*)(tmpB + bad0 + ij * (32 * 64));
    bf16x8 bf1 = *(const bf16x8*)(tmpB + bad1 + ij * (32 * 64));

    bf16x8 a[3];
    #pragma unroll
    for (int mi = 0; mi < 3; ++mi) {
      if (mi < nm) {
        int pos  = posb[mi] + sh;
        int byte = pos * 64 + ((hi ^ ((pos >> 1) & 3)) << 4);
        a[mi] = *(const bf16x8*)(detB + byte);
      }
    }
    #pragma unroll
    for (int mi = 0; mi < 3; ++mi) {
      if (mi < nm) {
        acc[mi][0] = __builtin_amdgcn_mfma_f32_16x16x32_bf16(a[mi], bf0, acc[mi][0], 0, 0, 0);
        acc[mi][1] = __builtin_amdgcn_mfma_f32_16x16x32_bf16(a[mi], bf1, acc[mi][1], 0, 0, 0);
      }
    }
  }

  // ---- store partial tile (plain stores, no atomics) ----
  float* __restrict__ pws = ws + ((size_t)q * NB + b) * PTILE;
  #pragma unroll
  for (int mi = 0; mi < 3; ++mi) {
    if (mi < nm) {
      int m = w + mi * 8;
      #pragma unroll
      for (int n = 0; n < 2; ++n) {
        int o = n * 16 + lo;
        if (o < NO) {
          #pragma unroll
          for (int v = 0; v < 4; ++v) {
            int p = m * 16 + hi * 4 + v;   // C/D: row=(lane>>4)*4+reg, col=lane&15
            if (p < NP) pws[p * NO + o] = acc[mi][n][v];
          }
        }
      }
    }
  }
}

extern "C" void kernel_launch(void* const* d_in, const int* in_sizes, int n_in,
                              void* d_out, int out_size, void* d_ws, size_t ws_size,
                              hipStream_t stream) {
  (void)in_sizes; (void)n_in; (void)ws_size;
  const float* det = (const float*)d_in[0];
  const float* tmp = (const float*)d_in[1];
  float* out = (float*)d_out;
  float* ws  = (float*)d_ws;   // NQ * NB * PTILE * 4 = 11.8 MB partials

  siamese_kernel<<<dim3(NB * NQ), dim3(512), 0, stream>>>(det, tmp, ws);
  int n4 = out_size / 4;       // 369920/4 = 92480 float4, exact
  reduce_kernel<<<dim3((n4 + 255) / 256), dim3(256), 0, stream>>>(
      (const float4*)ws, (float4*)out, n4);
}

// Round 4
// 21.906 us; speedup vs baseline: 1.8120x; 1.0045x over previous
//
#include <hip/hip_runtime.h>
#include <hip/hip_bf16.h>

// SiameseConv: out[b,y,x,o] = sum_{i,j,c} det[b,y+i,x+j,c] * tmpl[b,i,j,c,o]
// det: [64,20,20,256] f32, tmpl: [64,4,4,256*20] f32 (last dim = [c][o]),
// out: [64,17,17,20] f32.
//
// Per-example GEMM C[289x20] = A[289x4096] x B[4096x20], K=(ij,c), K-split by
// channel chunk of 32 -> 512 blocks. Stage bf16 slices in LDS (swizzled),
// 16x16x32 bf16 MFMA, partials to d_ws + float4 tree-reduce (no atomics: R2
// showed cross-XCD atomicAdd contention was ~37us).
// R3: template staging was 10240 scalar stride-80B gathers per block (~64
// cache lines per wave-load => ~8-10us). Now: coalesced float4 loads (4
// consecutive o at fixed ij,c) + transpose via 4x ds_write_b16 into the
// swizzled [ij][o][c] LDS layout. Also use (__bf16) casts so the compiler
// emits v_cvt_pk_bf16_f32 instead of manual bit-twiddling.

typedef __bf16 bf16x8 __attribute__((ext_vector_type(8)));
typedef float f32x4 __attribute__((ext_vector_type(4)));

#define NB 64
#define C_TOT 256
#define CQ 32            // channels per block
#define NQ 8             // c-chunks (256/32)
#define NPOS 400         // 20*20 detection positions
#define NP 289           // 17*17 output positions
#define NO 20            // outputs per position
#define PTILE (NP * NO)  // 5780 floats per partial tile
#define DET_LDS_BYTES (NPOS * CQ * 2)      // 25600: [400 pos][32 c] bf16
#define TMP_LDS_BYTES (16 * 32 * CQ * 2)   // 32768: [16 ij][32 o][32 c] bf16

__device__ __forceinline__ unsigned short bfbits(float f) {
  __bf16 h = (__bf16)f;   // RNE on gfx950 (v_cvt_pk_bf16_f32 when paired)
  return __builtin_bit_cast(unsigned short, h);
}

// out[e] = sum_{q=0..7} ws[q*369920 + e], float4-vectorized.
__global__ __launch_bounds__(256)
void reduce_kernel(const float4* __restrict__ ws, float4* __restrict__ out, int n4) {
  int i = blockIdx.x * 256 + threadIdx.x;
  if (i >= n4) return;
  float4 s = ws[i];
  #pragma unroll
  for (int q = 1; q < NQ; ++q) {
    float4 v = ws[q * n4 + i];
    s.x += v.x; s.y += v.y; s.z += v.z; s.w += v.w;
  }
  out[i] = s;
}

__global__ __launch_bounds__(512, 4)
void siamese_kernel(const float* __restrict__ det,
                    const float* __restrict__ tmp,
                    float* __restrict__ ws) {
  __shared__ alignas(16) char lds[DET_LDS_BYTES + TMP_LDS_BYTES];
  char* detB = lds;
  char* tmpB = lds + DET_LDS_BYTES;

  const int tid = threadIdx.x;
  const int b   = blockIdx.x >> 3;   // / NQ
  const int q   = blockIdx.x & 7;    // % NQ
  const int c0  = q * CQ;

  // ---- stage detection slice [400][32] bf16, granule-swizzled ----
  // byte(pos, c) = pos*64 + (((c>>3) ^ ((pos>>1)&3))<<4) + (c&7)*2
  {
    const float* __restrict__ dsrc = det + (size_t)b * (NPOS * C_TOT);
    for (int it = tid; it < NPOS * CQ / 4; it += 512) {   // 3200 float4
      int pos = it >> 3;          // 8 float4 per pos
      int cg  = it & 7;
      const float4 v = *(const float4*)(dsrc + pos * C_TOT + c0 + cg * 4);
      unsigned long long pk =
          (unsigned long long)bfbits(v.x) |
          ((unsigned long long)bfbits(v.y) << 16) |
          ((unsigned long long)bfbits(v.z) << 32) |
          ((unsigned long long)bfbits(v.w) << 48);
      int byte = pos * 64 + (((cg >> 1) ^ ((pos >> 1) & 3)) << 4) + (cg & 1) * 8;
      *(unsigned long long*)(detB + byte) = pk;
    }
  }

  // ---- zero template pad rows (o in [20,32)) ----
  {
    for (int z = tid; z < 16 * 12 * 4; z += 512) {   // 768 x 16B
      int rr = z >> 2;
      int ij = rr / 12;
      int o  = 20 + (rr % 12);
      int byte = (ij * 32 + o) * 64 + (z & 3) * 16;
      *(uint4*)(tmpB + byte) = make_uint4(0u, 0u, 0u, 0u);
    }
  }

  // ---- stage template slice -> [ij][o][c_local] bf16, swizzled ----
  // COALESCED: thread loads float4 = 4 consecutive o at fixed (ij,c) from the
  // natural [ij][c][o] global layout, then transposes via 4x ds_write_b16.
  // byte(row=ij*32+o, c) = row*64 + (((c>>3) ^ ((o>>1)&3))<<4) + (c&7)*2
  {
    const float* __restrict__ tsrc = tmp + (size_t)b * (16 * C_TOT * NO);
    for (int it = tid; it < 16 * CQ * 5; it += 512) {   // 2560 float4
      int og = it % 5;               // o-group of 4
      int c  = (it / 5) & 31;        // c_local
      int ij = it / 160;
      const float4 v = *(const float4*)(tsrc + ij * (C_TOT * NO) + (c0 + c) * NO + og * 4);
      unsigned short s4[4] = { bfbits(v.x), bfbits(v.y), bfbits(v.z), bfbits(v.w) };
      int gbase = ((c & 7) * 2) + ((c >> 3) << 4);   // granule before o-xor
      #pragma unroll
      for (int k = 0; k < 4; ++k) {
        int o    = og * 4 + k;
        int byte = (ij * 32 + o) * 64 + (gbase ^ (((o >> 1) & 3) << 4));
        *(unsigned short*)(tmpB + byte) = s4[k];
      }
    }
  }

  __syncthreads();

  // ---- compute: 19 M-tiles x 2 N-tiles over 8 waves, 16 K-steps of 32 ----
  const int w    = tid >> 6;
  const int lane = tid & 63;
  const int lo   = lane & 15;
  const int hi   = lane >> 4;
  const int nm   = (w < 3) ? 3 : 2;   // waves 0-2 own 3 M-tiles, rest own 2

  int posb[3];
  #pragma unroll
  for (int mi = 0; mi < 3; ++mi) {
    int m = w + mi * 8;                // M-tile index (w, w+8, w+16)
    int p = m * 16 + lo;               // A-row for this lane
    if (p > NP - 1) p = NP - 1;        // clamp pad rows (discarded at store)
    posb[mi] = (p / 17) * 20 + (p % 17);
  }

  f32x4 acc[3][2] = {};

  const int o0   = lo;                 // N-tile 0 col
  const int o1   = 16 + lo;            // N-tile 1 col (>=20 reads zeros)
  const int bad0 = o0 * 64 + ((hi ^ ((o0 >> 1) & 3)) << 4);
  const int bad1 = o1 * 64 + ((hi ^ ((o1 >> 1) & 3)) << 4);

  for (int ij = 0; ij < 16; ++ij) {
    const int i  = ij >> 2, j = ij & 3;
    const int sh = i * 20 + j;

    bf16x8 bf0 = *(const bf16x8*)(tmpB + bad0 + ij * (32 * 64));
    bf16x8 bf1 = *(const bf16x8*)(tmpB + bad1 + ij * (32 * 64));

    bf16x8 a[3];
    #pragma unroll
    for (int mi = 0; mi < 3; ++mi) {
      if (mi < nm) {
        int pos  = posb[mi] + sh;
        int byte = pos * 64 + ((hi ^ ((pos >> 1) & 3)) << 4);
        a[mi] = *(const bf16x8*)(detB + byte);
      }
    }
    #pragma unroll
    for (int mi = 0; mi < 3; ++mi) {
      if (mi < nm) {
        acc[mi][0] = __builtin_amdgcn_mfma_f32_16x16x32_bf16(a[mi], bf0, acc[mi][0], 0, 0, 0);
        acc[mi][1] = __builtin_amdgcn_mfma_f32_16x16x32_bf16(a[mi], bf1, acc[mi][1], 0, 0, 0);
      }
    }
  }

  // ---- store partial tile (plain stores, no atomics) ----
  float* __restrict__ pws = ws + ((size_t)q * NB + b) * PTILE;
  #pragma unroll
  for (int mi = 0; mi < 3; ++mi) {
    if (mi < nm) {
      int m = w + mi * 8;
      #pragma unroll
      for (int n = 0; n < 2; ++n) {
        int o = n * 16 + lo;
        if (o < NO) {
          #pragma unroll
          for (int v = 0; v < 4; ++v) {
            int p = m * 16 + hi * 4 + v;   // C/D: row=(lane>>4)*4+reg, col=lane&15
            if (p < NP) pws[p * NO + o] = acc[mi][n][v];
          }
        }
      }
    }
  }
}

extern "C" void kernel_launch(void* const* d_in, const int* in_sizes, int n_in,
                              void* d_out, int out_size, void* d_ws, size_t ws_size,
                              hipStream_t stream) {
  (void)in_sizes; (void)n_in; (void)ws_size;
  const float* det = (const float*)d_in[0];
  const float* tmp = (const float*)d_in[1];
  float* out = (float*)d_out;
  float* ws  = (float*)d_ws;   // NQ * NB * PTILE * 4 = 11.8 MB partials

  siamese_kernel<<<dim3(NB * NQ), dim3(512), 0, stream>>>(det, tmp, ws);
  int n4 = out_size / 4;       // 369920/4 = 92480 float4, exact
  reduce_kernel<<<dim3((n4 + 255) / 256), dim3(256), 0, stream>>>(
      (const float4*)ws, (float4*)out, n4);
}